// Round 3
// baseline (1315.894 us; speedup 1.0000x reference)
//
#include <hip/hip_runtime.h>

#define BATCH 256
#define TSTEPS 1024
#define NIN 128
#define NL 64
#define NH 128
#define NOUT 32

// ---------------------------------------------------------------------------
// Pass 0: transpose C [64][128] -> Ct [128][64]
// ---------------------------------------------------------------------------
__global__ void transpose_C_kernel(const float* __restrict__ C,
                                   float* __restrict__ Ct) {
    int gid = blockIdx.x * 256 + threadIdx.x;   // 8192 elements
    int l = gid & 63;
    int i = gid >> 6;
    Ct[gid] = C[l * NIN + i];   // Ct[i][l] = C[l][i]
}

// ---------------------------------------------------------------------------
// Pass 1: u[row, n] = sum_i s[row, i] * Ct[i, n]   (row = b*T + t)
// Register-tiled fp32 GEMM: block = 256 thr, tile M=128 x N=64, K chunked 16.
// Thread (tm,tn) computes 4 rows x 8 cols. 32 FMA : 3 ds_read per thread-k.
// ---------------------------------------------------------------------------
#define KC 16
#define AST 132   // At row stride (floats): 132*4=528 = 16*33, b128-aligned, depads conflicts
#define BST 68    // Bs row stride: 272 = 16*17

__launch_bounds__(256, 4)
__global__ void ugemm_kernel(const float* __restrict__ input,
                             const float* __restrict__ Ct,
                             float* __restrict__ u) {
    __shared__ float At[KC * AST];   // transposed A chunk: At[k][m]
    __shared__ float Bs[KC * BST];   // Bs[k][n]

    const int t = threadIdx.x;
    const long rowbase = (long)blockIdx.x * 128;
    const int tn = t & 7;            // col group (8 cols)
    const int tm = t >> 3;           // row group (4 rows)

    float acc[4][8];
    #pragma unroll
    for (int r = 0; r < 4; ++r)
        #pragma unroll
        for (int c = 0; c < 8; ++c) acc[r][c] = 0.f;

    const float4* in4 = (const float4*)input;
    const float4* Ct4 = (const float4*)Ct;

    for (int kc = 0; kc < NIN; kc += KC) {
        __syncthreads();   // protect LDS from previous chunk's readers
        // stage A chunk (128 rows x 16 k) transposed: 512 float4 loads
        #pragma unroll
        for (int j = 0; j < 2; ++j) {
            int idx = j * 256 + t;
            int m = idx >> 2, k4 = idx & 3;
            float4 v = in4[(rowbase + m) * 32 + (kc >> 2) + k4];
            At[(4 * k4 + 0) * AST + m] = v.x;
            At[(4 * k4 + 1) * AST + m] = v.y;
            At[(4 * k4 + 2) * AST + m] = v.z;
            At[(4 * k4 + 3) * AST + m] = v.w;
        }
        // stage B chunk (16 k x 64 n): 256 float4
        {
            int k = t >> 4, n4 = t & 15;
            float4 v = Ct4[(kc + k) * 16 + n4];
            *(float4*)&Bs[k * BST + n4 * 4] = v;
        }
        __syncthreads();

        #pragma unroll
        for (int k = 0; k < KC; ++k) {
            float4 a  = *(const float4*)&At[k * AST + tm * 4];
            float4 b0 = *(const float4*)&Bs[k * BST + tn * 8];
            float4 b1 = *(const float4*)&Bs[k * BST + tn * 8 + 4];
            float av[4] = {a.x, a.y, a.z, a.w};
            float bv[8] = {b0.x, b0.y, b0.z, b0.w, b1.x, b1.y, b1.z, b1.w};
            #pragma unroll
            for (int r = 0; r < 4; ++r)
                #pragma unroll
                for (int c = 0; c < 8; ++c)
                    acc[r][c] = fmaf(av[r], bv[c], acc[r][c]);
        }
    }

    float4* u4 = (float4*)u;
    #pragma unroll
    for (int r = 0; r < 4; ++r) {
        long row = rowbase + tm * 4 + r;
        u4[row * 16 + tn * 2 + 0] =
            make_float4(acc[r][0], acc[r][1], acc[r][2], acc[r][3]);
        u4[row * 16 + tn * 2 + 1] =
            make_float4(acc[r][4], acc[r][5], acc[r][6], acc[r][7]);
    }
}

// ---------------------------------------------------------------------------
// Pass 2: the scan. ONE WAVE per batch (grid 256 x 64 threads).
// No barriers: cross-lane exchange via LDS with wave-internal in-order DS +
// s_waitcnt lgkmcnt(0). u prefetched 2 steps ahead (vmcnt never drained).
// Lane l owns: hidden[l], hidden[l+64] (phase A), z[l] (phase B).
// Weights persistent in VGPRs: W2 rows l & l+64 (128), W1 row l (128).
// ---------------------------------------------------------------------------
__launch_bounds__(64, 1)
__global__ void plrnn_scan_kernel(const float* __restrict__ A,
                                  const float* __restrict__ W1,
                                  const float* __restrict__ W2,
                                  const float* __restrict__ h1,
                                  const float* __restrict__ h2,
                                  const float* __restrict__ u,
                                  const float* __restrict__ Wout,
                                  const float* __restrict__ bout,
                                  float* __restrict__ out) {
    __shared__ float zs[NL];
    __shared__ float hsa[NL];
    __shared__ float hsb[NL];

    const int l = threadIdx.x;
    const int b = blockIdx.x;

    float w2a[64], w2b[64], w1r[128];
    #pragma unroll
    for (int k4 = 0; k4 < 16; ++k4) {
        float4 v = ((const float4*)W2)[l * 16 + k4];          // W2[l][.]
        w2a[4*k4+0]=v.x; w2a[4*k4+1]=v.y; w2a[4*k4+2]=v.z; w2a[4*k4+3]=v.w;
        float4 w = ((const float4*)W2)[(l + 64) * 16 + k4];   // W2[l+64][.]
        w2b[4*k4+0]=w.x; w2b[4*k4+1]=w.y; w2b[4*k4+2]=w.z; w2b[4*k4+3]=w.w;
    }
    #pragma unroll
    for (int k4 = 0; k4 < 32; ++k4) {
        float4 v = ((const float4*)W1)[l * 32 + k4];          // W1[l][.]
        w1r[4*k4+0]=v.x; w1r[4*k4+1]=v.y; w1r[4*k4+2]=v.z; w1r[4*k4+3]=v.w;
    }
    const float ar  = A[l];
    const float h1r = h1[l];
    const float h2a = h2[l];
    const float h2b = h2[l + 64];

    const float* up = u + ((long)b << 16) + l;   // b*1024*64
    float zreg = 0.f;
    float uc  = up[0];
    float un1 = up[64];

    for (int t = 0; t < TSTEPS; ++t) {
        int tp = (t + 2 < TSTEPS) ? (t + 2) : (TSTEPS - 1);
        float un2 = up[tp * 64];                 // in-flight across the step

        // ---- publish z, phase A: hidden = relu(W2 @ z + h2) ----
        zs[l] = zreg;
        asm volatile("s_waitcnt lgkmcnt(0)" ::: "memory");
        float a0 = 0.f, a1 = 0.f, b0 = 0.f, b1 = 0.f;
        const float4* z4 = (const float4*)zs;
        #pragma unroll
        for (int k4 = 0; k4 < 16; ++k4) {
            float4 zv = z4[k4];                  // broadcast read
            a0 = fmaf(w2a[4*k4+0], zv.x, a0);
            a1 = fmaf(w2a[4*k4+1], zv.y, a1);
            a0 = fmaf(w2a[4*k4+2], zv.z, a0);
            a1 = fmaf(w2a[4*k4+3], zv.w, a1);
            b0 = fmaf(w2b[4*k4+0], zv.x, b0);
            b1 = fmaf(w2b[4*k4+1], zv.y, b1);
            b0 = fmaf(w2b[4*k4+2], zv.z, b0);
            b1 = fmaf(w2b[4*k4+3], zv.w, b1);
        }
        float ha = fmaxf(a0 + a1 + h2a, 0.f);
        float hb = fmaxf(b0 + b1 + h2b, 0.f);

        // ---- publish hidden, phase B: z' = A*z + W1 @ hidden + h1 + u ----
        hsa[l] = ha;
        hsb[l] = hb;
        asm volatile("s_waitcnt lgkmcnt(0)" ::: "memory");
        float c0 = 0.f, c1 = 0.f, c2 = 0.f, c3 = 0.f;
        const float4* ha4 = (const float4*)hsa;
        const float4* hb4 = (const float4*)hsb;
        #pragma unroll
        for (int j4 = 0; j4 < 16; ++j4) {
            float4 va = ha4[j4];                 // broadcast read
            c0 = fmaf(w1r[4*j4+0], va.x, c0);
            c1 = fmaf(w1r[4*j4+1], va.y, c1);
            c2 = fmaf(w1r[4*j4+2], va.z, c2);
            c3 = fmaf(w1r[4*j4+3], va.w, c3);
            float4 vb = hb4[j4];                 // broadcast read
            c0 = fmaf(w1r[64+4*j4+0], vb.x, c0);
            c1 = fmaf(w1r[64+4*j4+1], vb.y, c1);
            c2 = fmaf(w1r[64+4*j4+2], vb.z, c2);
            c3 = fmaf(w1r[64+4*j4+3], vb.w, c3);
        }
        float zn = fmaf(zreg, ar, ((c0 + c1) + (c2 + c3)) + h1r + uc);
        zn = fminf(fmaxf(zn, -5.f), 5.f);
        zreg = zn;
        uc = un1; un1 = un2;
    }

    // epilogue: out[b,o] = Wout[o,:] . z + bout[o]
    zs[l] = zreg;
    asm volatile("s_waitcnt lgkmcnt(0)" ::: "memory");
    if (l < NOUT) {
        float acc = bout[l];
        #pragma unroll
        for (int j = 0; j < NL; ++j)
            acc = fmaf(Wout[l * NL + j], zs[j], acc);
        out[b * NOUT + l] = acc;
    }
}

extern "C" void kernel_launch(void* const* d_in, const int* in_sizes, int n_in,
                              void* d_out, int out_size, void* d_ws, size_t ws_size,
                              hipStream_t stream) {
    const float* input = (const float*)d_in[0];
    const float* A     = (const float*)d_in[1];
    const float* W1    = (const float*)d_in[2];
    const float* W2    = (const float*)d_in[3];
    const float* h1    = (const float*)d_in[4];
    const float* h2    = (const float*)d_in[5];
    const float* C     = (const float*)d_in[6];
    const float* Wout  = (const float*)d_in[7];
    const float* bout  = (const float*)d_in[8];
    float* out = (float*)d_out;

    float* ws  = (float*)d_ws;
    float* Ct  = ws;            // 8192 floats
    float* u   = ws + 8192;     // 256*1024*64 floats = 64 MB

    transpose_C_kernel<<<dim3(32), dim3(256), 0, stream>>>(C, Ct);
    ugemm_kernel<<<dim3(2048), dim3(256), 0, stream>>>(input, Ct, u);
    plrnn_scan_kernel<<<dim3(BATCH), dim3(64), 0, stream>>>(
        A, W1, W2, h1, h2, u, Wout, bout, out);
}

// Round 4
// 1055.014 us; speedup vs baseline: 1.2473x; 1.2473x over previous
//
#include <hip/hip_runtime.h>
#include <hip/hip_bf16.h>

#define BATCH 256
#define TSTEPS 1024
#define NIN 128
#define NL 64
#define NH 128
#define NOUT 32

typedef __attribute__((ext_vector_type(8))) short short8;
typedef __attribute__((ext_vector_type(4))) float f32x4;

__device__ inline int pk2(float x, float y) {
    __hip_bfloat162 h = __float22bfloat162_rn(make_float2(x, y));
    union { __hip_bfloat162 h; int i; } u;
    u.h = h;
    return u.i;
}
__device__ inline short bf1(float x) {
    __hip_bfloat16 h = __float2bfloat16(x);
    union { __hip_bfloat16 h; short s; } u;
    u.h = h;
    return u.s;
}

// ---------------------------------------------------------------------------
// Pass 0: transpose C [64][128] -> Ct [128][64]
// ---------------------------------------------------------------------------
__global__ void transpose_C_kernel(const float* __restrict__ C,
                                   float* __restrict__ Ct) {
    int gid = blockIdx.x * 256 + threadIdx.x;   // 8192 elements
    int l = gid & 63;
    int i = gid >> 6;
    Ct[gid] = C[l * NIN + i];   // Ct[i][l] = C[l][i]
}

// ---------------------------------------------------------------------------
// Pass 1: u'[t][b][l] = (sum_i s[b,t,i] * Ct[i,l]) + h1[l], stored bf16.
// Register-tiled fp32 GEMM, 256 thr, tile M=128 x N=64, K chunked 16.
// ---------------------------------------------------------------------------
#define KC 16
#define AST 132
#define BST 68

__launch_bounds__(256, 4)
__global__ void ugemm_kernel(const float* __restrict__ input,
                             const float* __restrict__ Ct,
                             const float* __restrict__ h1,
                             unsigned short* __restrict__ u16) {
    __shared__ float At[KC * AST];   // At[k][m]
    __shared__ float Bs[KC * BST];   // Bs[k][n]

    const int t = threadIdx.x;
    const int b  = blockIdx.x >> 3;
    const int t0 = (blockIdx.x & 7) * 128;
    const long rowbase = (long)blockIdx.x * 128;
    const int tn = t & 7;            // col group (8 cols)
    const int tm = t >> 3;           // row group (4 rows)

    float h1v[8];
    #pragma unroll
    for (int i = 0; i < 8; ++i) h1v[i] = h1[tn * 8 + i];

    float acc[4][8];
    #pragma unroll
    for (int r = 0; r < 4; ++r)
        #pragma unroll
        for (int c = 0; c < 8; ++c) acc[r][c] = 0.f;

    const float4* in4 = (const float4*)input;
    const float4* Ct4 = (const float4*)Ct;

    for (int kc = 0; kc < NIN; kc += KC) {
        __syncthreads();
        #pragma unroll
        for (int j = 0; j < 2; ++j) {
            int idx = j * 256 + t;
            int m = idx >> 2, k4 = idx & 3;
            float4 v = in4[(rowbase + m) * 32 + (kc >> 2) + k4];
            At[(4 * k4 + 0) * AST + m] = v.x;
            At[(4 * k4 + 1) * AST + m] = v.y;
            At[(4 * k4 + 2) * AST + m] = v.z;
            At[(4 * k4 + 3) * AST + m] = v.w;
        }
        {
            int k = t >> 4, n4 = t & 15;
            float4 v = Ct4[(kc + k) * 16 + n4];
            *(float4*)&Bs[k * BST + n4 * 4] = v;
        }
        __syncthreads();

        #pragma unroll
        for (int k = 0; k < KC; ++k) {
            float4 a  = *(const float4*)&At[k * AST + tm * 4];
            float4 b0 = *(const float4*)&Bs[k * BST + tn * 8];
            float4 b1 = *(const float4*)&Bs[k * BST + tn * 8 + 4];
            float av[4] = {a.x, a.y, a.z, a.w};
            float bv[8] = {b0.x, b0.y, b0.z, b0.w, b1.x, b1.y, b1.z, b1.w};
            #pragma unroll
            for (int r = 0; r < 4; ++r)
                #pragma unroll
                for (int c = 0; c < 8; ++c)
                    acc[r][c] = fmaf(av[r], bv[c], acc[r][c]);
        }
    }

    // store bf16 in scan-friendly layout [t][b][latent], with h1 folded in
    #pragma unroll
    for (int r = 0; r < 4; ++r) {
        int tt = t0 + tm * 4 + r;
        int p0 = pk2(acc[r][0] + h1v[0], acc[r][1] + h1v[1]);
        int p1 = pk2(acc[r][2] + h1v[2], acc[r][3] + h1v[3]);
        int p2 = pk2(acc[r][4] + h1v[4], acc[r][5] + h1v[5]);
        int p3 = pk2(acc[r][6] + h1v[6], acc[r][7] + h1v[7]);
        *(int4*)&u16[((size_t)tt * 256 + b) * 64 + tn * 8] =
            make_int4(p0, p1, p2, p3);
    }
}

// ---------------------------------------------------------------------------
// Pass 2: MFMA scan. One wave per 16 batches (grid 16 x 64 thr), no barriers.
// State Z^T [64 latent x 16 batch] as 4 C-frags (fp32). Per step:
//   H^T = relu(W2 @ Z^T + h2)  -- 16x mfma_f32_16x16x32_bf16 (W2 A-frags static)
//   Z'  = clip(A.z + W1 @ H^T + u')  -- 16x mfma (W1 A-frags static)
// C->B frag transform via wave-local LDS (bf16), in-order DS + lgkmcnt only.
// ---------------------------------------------------------------------------
__global__
__attribute__((amdgpu_flat_work_group_size(64, 64), amdgpu_waves_per_eu(1, 1)))
void plrnn_scan_mfma(const float* __restrict__ A,
                     const float* __restrict__ W1,
                     const float* __restrict__ W2,
                     const float* __restrict__ h2,
                     const unsigned short* __restrict__ u16,
                     const float* __restrict__ Wout,
                     const float* __restrict__ bout,
                     float* __restrict__ out) {
    __shared__ __attribute__((aligned(16))) unsigned short zlds[16 * 72];
    __shared__ __attribute__((aligned(16))) unsigned short hlds[16 * 136];

    const int lane = threadIdx.x;
    const int c = lane & 15;        // batch col within group
    const int q = lane >> 4;        // quad
    const int bbase = blockIdx.x * 16;

    // ---- static weight fragments (bf16) ----
    short8 aw2[8][2];
    #pragma unroll
    for (int mt = 0; mt < 8; ++mt)
        #pragma unroll
        for (int kt = 0; kt < 2; ++kt) {
            const float* p = W2 + (mt * 16 + c) * NL + kt * 32 + q * 8;
            short8 f;
            #pragma unroll
            for (int j = 0; j < 8; ++j) f[j] = bf1(p[j]);
            aw2[mt][kt] = f;
        }
    short8 aw1[4][4];
    #pragma unroll
    for (int lt = 0; lt < 4; ++lt)
        #pragma unroll
        for (int kt = 0; kt < 4; ++kt) {
            const float* p = W1 + (lt * 16 + c) * NH + kt * 32 + q * 8;
            short8 f;
            #pragma unroll
            for (int j = 0; j < 8; ++j) f[j] = bf1(p[j]);
            aw1[lt][kt] = f;
        }
    f32x4 h2f[8];
    #pragma unroll
    for (int mt = 0; mt < 8; ++mt)
        h2f[mt] = *(const f32x4*)(h2 + mt * 16 + q * 4);
    f32x4 af[4];
    #pragma unroll
    for (int lt = 0; lt < 4; ++lt)
        af[lt] = *(const f32x4*)(A + lt * 16 + q * 4);

    f32x4 zf[4] = {{0,0,0,0},{0,0,0,0},{0,0,0,0},{0,0,0,0}};

    // u' base for this lane's batch; step offset = t*16384 + lt*16 + q*4
    const unsigned short* ub = u16 + (size_t)(bbase + c) * 64;
    int2 ucur[4], unx[4];
    #pragma unroll
    for (int lt = 0; lt < 4; ++lt) {
        ucur[lt] = *(const int2*)(ub + lt * 16 + q * 4);
        unx[lt]  = *(const int2*)(ub + 16384 + lt * 16 + q * 4);
    }

    for (int t = 0; t < TSTEPS; ++t) {
        // ---- publish z as bf16 ----
        #pragma unroll
        for (int lt = 0; lt < 4; ++lt) {
            int p0 = pk2(zf[lt][0], zf[lt][1]);
            int p1 = pk2(zf[lt][2], zf[lt][3]);
            *(int2*)&zlds[c * 72 + lt * 16 + q * 4] = make_int2(p0, p1);
        }
        asm volatile("s_waitcnt lgkmcnt(0)" ::: "memory");
        short8 bz0 = *(short8*)&zlds[c * 72 + q * 8];
        short8 bz1 = *(short8*)&zlds[c * 72 + 32 + q * 8];

        // prefetch u' for t+2
        int tp = (t + 2 < TSTEPS) ? t + 2 : TSTEPS - 1;
        int2 upf[4];
        #pragma unroll
        for (int lt = 0; lt < 4; ++lt)
            upf[lt] = *(const int2*)(ub + (size_t)tp * 16384 + lt * 16 + q * 4);

        // ---- MFMA1: H^T = relu(W2 @ Z^T + h2) ----
        #pragma unroll
        for (int mt = 0; mt < 8; ++mt) {
            f32x4 acc = __builtin_amdgcn_mfma_f32_16x16x32_bf16(
                aw2[mt][0], bz0, h2f[mt], 0, 0, 0);
            acc = __builtin_amdgcn_mfma_f32_16x16x32_bf16(
                aw2[mt][1], bz1, acc, 0, 0, 0);
            int p0 = pk2(fmaxf(acc[0], 0.f), fmaxf(acc[1], 0.f));
            int p1 = pk2(fmaxf(acc[2], 0.f), fmaxf(acc[3], 0.f));
            *(int2*)&hlds[c * 136 + mt * 16 + q * 4] = make_int2(p0, p1);
        }
        asm volatile("s_waitcnt lgkmcnt(0)" ::: "memory");
        short8 bh0 = *(short8*)&hlds[c * 136 + q * 8];
        short8 bh1 = *(short8*)&hlds[c * 136 + 32 + q * 8];
        short8 bh2 = *(short8*)&hlds[c * 136 + 64 + q * 8];
        short8 bh3 = *(short8*)&hlds[c * 136 + 96 + q * 8];

        // ---- MFMA2: Z' = clip(A.z + u' + W1 @ H^T) ----
        #pragma unroll
        for (int lt = 0; lt < 4; ++lt) {
            int d0 = ucur[lt].x, d1 = ucur[lt].y;
            f32x4 cin;
            cin[0] = fmaf(zf[lt][0], af[lt][0], __int_as_float(d0 << 16));
            cin[1] = fmaf(zf[lt][1], af[lt][1], __int_as_float(d0 & 0xffff0000));
            cin[2] = fmaf(zf[lt][2], af[lt][2], __int_as_float(d1 << 16));
            cin[3] = fmaf(zf[lt][3], af[lt][3], __int_as_float(d1 & 0xffff0000));
            f32x4 acc = __builtin_amdgcn_mfma_f32_16x16x32_bf16(
                aw1[lt][0], bh0, cin, 0, 0, 0);
            acc = __builtin_amdgcn_mfma_f32_16x16x32_bf16(
                aw1[lt][1], bh1, acc, 0, 0, 0);
            acc = __builtin_amdgcn_mfma_f32_16x16x32_bf16(
                aw1[lt][2], bh2, acc, 0, 0, 0);
            acc = __builtin_amdgcn_mfma_f32_16x16x32_bf16(
                aw1[lt][3], bh3, acc, 0, 0, 0);
            #pragma unroll
            for (int e = 0; e < 4; ++e)
                zf[lt][e] = fminf(fmaxf(acc[e], -5.f), 5.f);
            ucur[lt] = unx[lt];
            unx[lt]  = upf[lt];
        }
    }

    // ---- epilogue: out^T = Wout @ Z^T + bout ----
    #pragma unroll
    for (int lt = 0; lt < 4; ++lt) {
        int p0 = pk2(zf[lt][0], zf[lt][1]);
        int p1 = pk2(zf[lt][2], zf[lt][3]);
        *(int2*)&zlds[c * 72 + lt * 16 + q * 4] = make_int2(p0, p1);
    }
    asm volatile("s_waitcnt lgkmcnt(0)" ::: "memory");
    short8 fz0 = *(short8*)&zlds[c * 72 + q * 8];
    short8 fz1 = *(short8*)&zlds[c * 72 + 32 + q * 8];
    #pragma unroll
    for (int ot = 0; ot < 2; ++ot) {
        const float* p0 = Wout + (ot * 16 + c) * NL + q * 8;
        const float* p1 = Wout + (ot * 16 + c) * NL + 32 + q * 8;
        short8 fa, fb;
        #pragma unroll
        for (int j = 0; j < 8; ++j) { fa[j] = bf1(p0[j]); fb[j] = bf1(p1[j]); }
        f32x4 cb = *(const f32x4*)(bout + ot * 16 + q * 4);
        f32x4 acc = __builtin_amdgcn_mfma_f32_16x16x32_bf16(fa, fz0, cb, 0, 0, 0);
        acc = __builtin_amdgcn_mfma_f32_16x16x32_bf16(fb, fz1, acc, 0, 0, 0);
        *(f32x4*)&out[(bbase + c) * 32 + ot * 16 + q * 4] = acc;
    }
}

extern "C" void kernel_launch(void* const* d_in, const int* in_sizes, int n_in,
                              void* d_out, int out_size, void* d_ws, size_t ws_size,
                              hipStream_t stream) {
    const float* input = (const float*)d_in[0];
    const float* A     = (const float*)d_in[1];
    const float* W1    = (const float*)d_in[2];
    const float* W2    = (const float*)d_in[3];
    const float* h1    = (const float*)d_in[4];
    const float* h2    = (const float*)d_in[5];
    const float* C     = (const float*)d_in[6];
    const float* Wout  = (const float*)d_in[7];
    const float* bout  = (const float*)d_in[8];
    float* out = (float*)d_out;

    float* ws = (float*)d_ws;
    float* Ct = ws;                                      // 8192 floats
    unsigned short* u16 = (unsigned short*)(ws + 8192);  // 256*1024*64 bf16 = 33.5 MB

    transpose_C_kernel<<<dim3(32), dim3(256), 0, stream>>>(C, Ct);
    ugemm_kernel<<<dim3(2048), dim3(256), 0, stream>>>(input, Ct, h1, u16);
    plrnn_scan_mfma<<<dim3(16), dim3(64), 0, stream>>>(
        A, W1, W2, h2, u16, Wout, bout, out);
}

// Round 5
// 699.072 us; speedup vs baseline: 1.8823x; 1.5092x over previous
//
#include <hip/hip_runtime.h>
#include <hip/hip_bf16.h>

#define BATCH 256
#define TSTEPS 1024
#define NIN 128
#define NL 64
#define NH 128
#define NOUT 32

typedef __attribute__((ext_vector_type(8))) short short8;
typedef __attribute__((ext_vector_type(4))) float f32x4;

__device__ inline int pk2(float x, float y) {
    __hip_bfloat162 h = __float22bfloat162_rn(make_float2(x, y));
    union { __hip_bfloat162 h; int i; } u;
    u.h = h;
    return u.i;
}
__device__ inline short bf1(float x) {
    __hip_bfloat16 h = __float2bfloat16(x);
    union { __hip_bfloat16 h; short s; } u;
    u.h = h;
    return u.s;
}

#define WG_BARRIER() asm volatile("s_waitcnt lgkmcnt(0)\n\ts_barrier" ::: "memory")

// ---------------------------------------------------------------------------
// Pass 1: u'[t][b][l] = bf16( C[l,:]·s[b,t,:] + h1[l] )
// MFMA GEMM, LDS-free. A = C (latent x input), static frags; B = s^T loaded
// global->VGPR with 1-iter prefetch; D rows = latent -> contiguous b64 stores.
// Grid: 512 WGs x 256 thr; wave handles 8 n-tiles (16 t-rows each).
// ---------------------------------------------------------------------------
__launch_bounds__(256, 1)
__global__ void ugemm_mfma(const float* __restrict__ input,
                           const float* __restrict__ C,
                           const float* __restrict__ h1,
                           unsigned short* __restrict__ u16) {
    const int lane = threadIdx.x & 63;
    const int wv   = threadIdx.x >> 6;
    const int c = lane & 15;
    const int q = lane >> 4;
    const long wbase = ((long)blockIdx.x * 4 + wv) * 128;  // first row (b*1024+t)

    // static A-frags: cA[mt][kf] = C[(mt*16+c), kf*32+q*8 .. +7] bf16
    short8 cA[4][4];
    #pragma unroll
    for (int mt = 0; mt < 4; ++mt)
        #pragma unroll
        for (int kf = 0; kf < 4; ++kf) {
            const float* p = C + (mt * 16 + c) * NIN + kf * 32 + q * 8;
            float4 r0 = *(const float4*)p;
            float4 r1 = *(const float4*)(p + 4);
            union { short8 s; int i[4]; } f;
            f.i[0] = pk2(r0.x, r0.y); f.i[1] = pk2(r0.z, r0.w);
            f.i[2] = pk2(r1.x, r1.y); f.i[3] = pk2(r1.z, r1.w);
            cA[mt][kf] = f.s;
        }
    f32x4 h1f[4];
    #pragma unroll
    for (int mt = 0; mt < 4; ++mt)
        h1f[mt] = *(const f32x4*)(h1 + mt * 16 + q * 4);

    // prefetch it=0 raw rows
    float4 raw[8], rawn[8];
    {
        const float* sr = input + (wbase + c) * NIN;
        #pragma unroll
        for (int kf = 0; kf < 4; ++kf) {
            raw[2*kf]   = *(const float4*)(sr + kf * 32 + q * 8);
            raw[2*kf+1] = *(const float4*)(sr + kf * 32 + q * 8 + 4);
        }
    }

    for (int it = 0; it < 8; ++it) {
        // prefetch next iteration's rows
        if (it < 7) {
            const float* sr = input + (wbase + (it + 1) * 16 + c) * NIN;
            #pragma unroll
            for (int kf = 0; kf < 4; ++kf) {
                rawn[2*kf]   = *(const float4*)(sr + kf * 32 + q * 8);
                rawn[2*kf+1] = *(const float4*)(sr + kf * 32 + q * 8 + 4);
            }
        }
        // convert to B-frags
        short8 bf[4];
        #pragma unroll
        for (int kf = 0; kf < 4; ++kf) {
            union { short8 s; int i[4]; } f;
            f.i[0] = pk2(raw[2*kf].x,   raw[2*kf].y);
            f.i[1] = pk2(raw[2*kf].z,   raw[2*kf].w);
            f.i[2] = pk2(raw[2*kf+1].x, raw[2*kf+1].y);
            f.i[3] = pk2(raw[2*kf+1].z, raw[2*kf+1].w);
            bf[kf] = f.s;
        }
        // MFMA: D[latent, t] for 4 latent tiles
        long rr = wbase + it * 16 + c;       // this lane's t-row (column n=c)
        int b = (int)(rr >> 10), t = (int)(rr & 1023);
        unsigned short* ubase = u16 + ((size_t)t * 256 + b) * 64 + q * 4;
        #pragma unroll
        for (int mt = 0; mt < 4; ++mt) {
            f32x4 acc = __builtin_amdgcn_mfma_f32_16x16x32_bf16(cA[mt][0], bf[0], h1f[mt], 0, 0, 0);
            acc = __builtin_amdgcn_mfma_f32_16x16x32_bf16(cA[mt][1], bf[1], acc, 0, 0, 0);
            acc = __builtin_amdgcn_mfma_f32_16x16x32_bf16(cA[mt][2], bf[2], acc, 0, 0, 0);
            acc = __builtin_amdgcn_mfma_f32_16x16x32_bf16(cA[mt][3], bf[3], acc, 0, 0, 0);
            *(int2*)(ubase + mt * 16) =
                make_int2(pk2(acc[0], acc[1]), pk2(acc[2], acc[3]));
        }
        #pragma unroll
        for (int j = 0; j < 8; ++j) raw[j] = rawn[j];
    }
}

// ---------------------------------------------------------------------------
// Pass 2: MFMA scan, M-split over 4 waves. Grid 16 WGs x 256 thr; WG = one
// group of 16 batches. Wave w: H rows [32w,32w+32) (2 tiles), Z rows
// [16w,16w+16) (1 tile). Manual lgkmcnt+s_barrier (vmcnt stays in flight).
// ---------------------------------------------------------------------------
__launch_bounds__(256, 1)
__global__ void plrnn_scan_mfma(const float* __restrict__ A,
                                const float* __restrict__ W1,
                                const float* __restrict__ W2,
                                const float* __restrict__ h2,
                                const unsigned short* __restrict__ u16,
                                const float* __restrict__ Wout,
                                const float* __restrict__ bout,
                                float* __restrict__ out) {
    __shared__ __attribute__((aligned(16))) unsigned short zbuf[16 * 72];
    __shared__ __attribute__((aligned(16))) unsigned short hbuf[16 * 136];

    const int lane = threadIdx.x & 63;
    const int w    = threadIdx.x >> 6;     // wave 0..3
    const int c = lane & 15;               // batch col
    const int q = lane >> 4;               // quad
    const int bbase = blockIdx.x * 16;

    // ---- static weight fragments ----
    short8 aw2[2][2];   // H tiles mt = 2w, 2w+1 ; K = 64 (2 frags)
    #pragma unroll
    for (int i = 0; i < 2; ++i)
        #pragma unroll
        for (int kt = 0; kt < 2; ++kt) {
            const float* p = W2 + ((2*w + i) * 16 + c) * NL + kt * 32 + q * 8;
            short8 f;
            #pragma unroll
            for (int j = 0; j < 8; ++j) f[j] = bf1(p[j]);
            aw2[i][kt] = f;
        }
    short8 aw1[4];      // Z tile lt = w ; K = 128 (4 frags)
    #pragma unroll
    for (int kt = 0; kt < 4; ++kt) {
        const float* p = W1 + (w * 16 + c) * NH + kt * 32 + q * 8;
        short8 f;
        #pragma unroll
        for (int j = 0; j < 8; ++j) f[j] = bf1(p[j]);
        aw1[kt] = f;
    }
    f32x4 h2f[2];
    #pragma unroll
    for (int i = 0; i < 2; ++i)
        h2f[i] = *(const f32x4*)(h2 + (2*w + i) * 16 + q * 4);
    const f32x4 af = *(const f32x4*)(A + w * 16 + q * 4);

    f32x4 zf = {0.f, 0.f, 0.f, 0.f};

    // u' stream: index (t*256 + bbase+c)*64 + w*16 + q*4 ; stride/t = 16384
    const unsigned short* ub = u16 + ((size_t)(bbase + c)) * 64 + w * 16 + q * 4;
    int2 ucur = *(const int2*)ub;
    int2 unx  = *(const int2*)(ub + 16384);

    for (int t = 0; t < TSTEPS; ++t) {
        // ---- publish z (wave w owns latents [16w,16w+16)) ----
        *(int2*)&zbuf[c * 72 + w * 16 + q * 4] =
            make_int2(pk2(zf[0], zf[1]), pk2(zf[2], zf[3]));
        WG_BARRIER();
        short8 bz0 = *(short8*)&zbuf[c * 72 + q * 8];
        short8 bz1 = *(short8*)&zbuf[c * 72 + 32 + q * 8];

        // prefetch u'(t+2) — stays in flight across both MFMA phases
        int tp = (t + 2 < TSTEPS) ? t + 2 : TSTEPS - 1;
        int2 upf = *(const int2*)(ub + (size_t)tp * 16384);

        // ---- MFMA1: H rows [32w,32w+32) = relu(W2 @ Z + h2) ----
        #pragma unroll
        for (int i = 0; i < 2; ++i) {
            f32x4 acc = __builtin_amdgcn_mfma_f32_16x16x32_bf16(aw2[i][0], bz0, h2f[i], 0, 0, 0);
            acc = __builtin_amdgcn_mfma_f32_16x16x32_bf16(aw2[i][1], bz1, acc, 0, 0, 0);
            *(int2*)&hbuf[c * 136 + (2*w + i) * 16 + q * 4] =
                make_int2(pk2(fmaxf(acc[0], 0.f), fmaxf(acc[1], 0.f)),
                          pk2(fmaxf(acc[2], 0.f), fmaxf(acc[3], 0.f)));
        }
        WG_BARRIER();
        short8 bh0 = *(short8*)&hbuf[c * 136 + q * 8];
        short8 bh1 = *(short8*)&hbuf[c * 136 + 32 + q * 8];
        short8 bh2 = *(short8*)&hbuf[c * 136 + 64 + q * 8];
        short8 bh3 = *(short8*)&hbuf[c * 136 + 96 + q * 8];

        // ---- MFMA2: Z' rows [16w,16w+16) = clip(A.z + u' + W1 @ H) ----
        f32x4 cin;
        cin[0] = fmaf(zf[0], af[0], __int_as_float(ucur.x << 16));
        cin[1] = fmaf(zf[1], af[1], __int_as_float(ucur.x & 0xffff0000));
        cin[2] = fmaf(zf[2], af[2], __int_as_float(ucur.y << 16));
        cin[3] = fmaf(zf[3], af[3], __int_as_float(ucur.y & 0xffff0000));
        f32x4 acc = __builtin_amdgcn_mfma_f32_16x16x32_bf16(aw1[0], bh0, cin, 0, 0, 0);
        acc = __builtin_amdgcn_mfma_f32_16x16x32_bf16(aw1[1], bh1, acc, 0, 0, 0);
        acc = __builtin_amdgcn_mfma_f32_16x16x32_bf16(aw1[2], bh2, acc, 0, 0, 0);
        acc = __builtin_amdgcn_mfma_f32_16x16x32_bf16(aw1[3], bh3, acc, 0, 0, 0);
        #pragma unroll
        for (int e = 0; e < 4; ++e)
            zf[e] = fminf(fmaxf(acc[e], -5.f), 5.f);
        ucur = unx;
        unx  = upf;
    }

    // ---- epilogue: out = Wout @ Z + bout (waves 0,1) ----
    *(int2*)&zbuf[c * 72 + w * 16 + q * 4] =
        make_int2(pk2(zf[0], zf[1]), pk2(zf[2], zf[3]));
    WG_BARRIER();
    if (w < 2) {
        short8 fz0 = *(short8*)&zbuf[c * 72 + q * 8];
        short8 fz1 = *(short8*)&zbuf[c * 72 + 32 + q * 8];
        const float* p0 = Wout + (w * 16 + c) * NL + q * 8;
        const float* p1 = p0 + 32;
        short8 fa, fb;
        #pragma unroll
        for (int j = 0; j < 8; ++j) { fa[j] = bf1(p0[j]); fb[j] = bf1(p1[j]); }
        f32x4 cb = *(const f32x4*)(bout + w * 16 + q * 4);
        f32x4 acc = __builtin_amdgcn_mfma_f32_16x16x32_bf16(fa, fz0, cb, 0, 0, 0);
        acc = __builtin_amdgcn_mfma_f32_16x16x32_bf16(fb, fz1, acc, 0, 0, 0);
        *(f32x4*)&out[(bbase + c) * 32 + w * 16 + q * 4] = acc;
    }
}

extern "C" void kernel_launch(void* const* d_in, const int* in_sizes, int n_in,
                              void* d_out, int out_size, void* d_ws, size_t ws_size,
                              hipStream_t stream) {
    const float* input = (const float*)d_in[0];
    const float* A     = (const float*)d_in[1];
    const float* W1    = (const float*)d_in[2];
    const float* W2    = (const float*)d_in[3];
    const float* h1    = (const float*)d_in[4];
    const float* h2    = (const float*)d_in[5];
    const float* C     = (const float*)d_in[6];
    const float* Wout  = (const float*)d_in[7];
    const float* bout  = (const float*)d_in[8];
    float* out = (float*)d_out;

    unsigned short* u16 = (unsigned short*)d_ws;   // 256*1024*64 bf16 = 33.5 MB

    ugemm_mfma<<<dim3(512), dim3(256), 0, stream>>>(input, C, h1, u16);
    plrnn_scan_mfma<<<dim3(16), dim3(256), 0, stream>>>(
        A, W1, W2, h2, u16, Wout, bout, out);
}